// Round 4
// baseline (158.219 us; speedup 1.0000x reference)
//
#include <hip/hip_runtime.h>

// TvarLayer: out[b, (n*C+c)*9+k, l] = (p_k*W[n,c,k] - mean_k(p*W))^2 / sum_k(W[n,c,k]) + Bbias[n,c]
// B=4, N=8, C=8, K=9 (3x3, pad 1, stride 1), H=W=128, L=16384.
// Write-BW-bound: 151 MB out vs 2 MB in. Floor ~24 us @ 6.3 TB/s.
//
// R2: split n across blocks (8x more waves: 2 -> 16 waves/SIMD of work) so the
// write pipe stays saturated; (b,n,c) block-uniform -> weights via scalar loads,
// no LDS, no syncthreads.

#define BB 4
#define NN 8
#define CC 8
#define KK 9
#define HH 128
#define WW 128
#define LL (HH * WW)

typedef float vf4 __attribute__((ext_vector_type(4)));

__global__ __launch_bounds__(256) void tvar_kernel(
    const float* __restrict__ arr,
    const float* __restrict__ Wt,
    const float* __restrict__ Bb,
    float* __restrict__ out)
{
    // block: bid = b(2) | n(3) | c(3) | hi(4);  thread: hlo(3) | w4(5)
    const int bid = blockIdx.x;
    const int hi = bid & 15;
    const int c  = (bid >> 4) & 7;
    const int n  = (bid >> 7) & 7;
    const int b  = bid >> 10;

    const int lt = threadIdx.x;
    const int w4 = lt & 31;
    const int h  = (hi << 3) | (lt >> 5);

    // block-uniform -> scalar loads
    const float* wrow = Wt + (n * CC + c) * KK;
    float w9[KK];
    float wsum = 0.f;
    #pragma unroll
    for (int k = 0; k < KK; ++k) { w9[k] = wrow[k]; wsum += w9[k]; }
    const float sinv = 1.0f / wsum;
    const float bias = Bb[n * CC + c];

    // Load 3x6 patch (rows h-1..h+1, cols ws-1..ws+4), zero-padded.
    const int ws = w4 << 2;
    const float* abase = arr + (size_t)((b * CC + c) * HH) * WW;
    float p[3][6];
    #pragma unroll
    for (int r = 0; r < 3; ++r) {
        const int hh = h + r - 1;
        if (hh >= 0 && hh < HH) {
            const float* row = abase + hh * WW + ws;
            const float4 v = *(const float4*)row;          // ws is 16B-aligned
            p[r][1] = v.x; p[r][2] = v.y; p[r][3] = v.z; p[r][4] = v.w;
            p[r][0] = (ws > 0)      ? row[-1] : 0.f;
            p[r][5] = (ws + 4 < WW) ? row[4]  : 0.f;
        } else {
            #pragma unroll
            for (int j = 0; j < 6; ++j) p[r][j] = 0.f;
        }
    }

    const float inv9 = 1.0f / 9.0f;
    float mean[4] = {0.f, 0.f, 0.f, 0.f};
    #pragma unroll
    for (int k = 0; k < KK; ++k) {
        const int kh = k / 3, kw = k - kh * 3;
        #pragma unroll
        for (int j = 0; j < 4; ++j)
            mean[j] += p[kh][j + kw] * w9[k];
    }
    #pragma unroll
    for (int j = 0; j < 4; ++j) mean[j] *= inv9;

    float* onb = out + (size_t)b * (NN * CC * KK) * LL
                     + (size_t)((n * CC + c) * KK) * LL
                     + (size_t)(h * WW + ws);
    #pragma unroll
    for (int k = 0; k < KK; ++k) {
        const int kh = k / 3, kw = k - kh * 3;
        vf4 o;
        #pragma unroll
        for (int j = 0; j < 4; ++j) {
            const float v = p[kh][j + kw] * w9[k];
            const float d = v - mean[j];
            o[j] = d * d * sinv + bias;
        }
        // streaming store: output (151 MB) >> L2 (32 MB), never re-read
        __builtin_nontemporal_store(o, (vf4*)(onb + (size_t)k * LL));
    }
}

extern "C" void kernel_launch(void* const* d_in, const int* in_sizes, int n_in,
                              void* d_out, int out_size, void* d_ws, size_t ws_size,
                              hipStream_t stream) {
    const float* arr = (const float*)d_in[0];
    const float* Wt  = (const float*)d_in[1];
    const float* Bb  = (const float*)d_in[2];
    float* out = (float*)d_out;

    // threads total = B*N*C*H*(W/4) = 4*8*8*128*32 = 1,048,576 -> 4096 blocks
    const int threads = 256;
    const int blocks = BB * NN * CC * 16;  // 4096
    tvar_kernel<<<blocks, threads, 0, stream>>>(arr, Wt, Bb, out);
}

// Round 5
// 154.395 us; speedup vs baseline: 1.0248x; 1.0248x over previous
//
#include <hip/hip_runtime.h>

// TvarLayer: out[b, (n*C+c)*9+k, l] = (p_k*W[n,c,k] - mean_k(p*W))^2 / sum_k(W[n,c,k]) + Bbias[n,c]
// B=4, N=8, C=8, K=9 (3x3, pad 1, stride 1), H=W=128, L=16384.
// Write-BW-bound: 151 MB out vs 2 MB in. Floor ~24 us @ 6.3 TB/s.
//
// R2: n split across blocks (4096 blocks), scalar weight loads, no LDS.  -> NEUTRAL (kernel ~63us both ways)
// R5: drop __builtin_nontemporal_store -> regular cached stores. The harness's own
//     fillBufferAligned proves regular stores to a >L2 buffer stream at 6.35 TB/s;
//     NT bypasses L2's write path and measured only ~2.4 TB/s.

#define BB 4
#define NN 8
#define CC 8
#define KK 9
#define HH 128
#define WW 128
#define LL (HH * WW)

typedef float vf4 __attribute__((ext_vector_type(4)));

__global__ __launch_bounds__(256) void tvar_kernel(
    const float* __restrict__ arr,
    const float* __restrict__ Wt,
    const float* __restrict__ Bb,
    float* __restrict__ out)
{
    // block: bid = b(2) | n(3) | c(3) | hi(4);  thread: hlo(3) | w4(5)
    const int bid = blockIdx.x;
    const int hi = bid & 15;
    const int c  = (bid >> 4) & 7;
    const int n  = (bid >> 7) & 7;
    const int b  = bid >> 10;

    const int lt = threadIdx.x;
    const int w4 = lt & 31;
    const int h  = (hi << 3) | (lt >> 5);

    // block-uniform -> scalar loads
    const float* wrow = Wt + (n * CC + c) * KK;
    float w9[KK];
    float wsum = 0.f;
    #pragma unroll
    for (int k = 0; k < KK; ++k) { w9[k] = wrow[k]; wsum += w9[k]; }
    const float sinv = 1.0f / wsum;
    const float bias = Bb[n * CC + c];

    // Load 3x6 patch (rows h-1..h+1, cols ws-1..ws+4), zero-padded.
    const int ws = w4 << 2;
    const float* abase = arr + (size_t)((b * CC + c) * HH) * WW;
    float p[3][6];
    #pragma unroll
    for (int r = 0; r < 3; ++r) {
        const int hh = h + r - 1;
        if (hh >= 0 && hh < HH) {
            const float* row = abase + hh * WW + ws;
            const float4 v = *(const float4*)row;          // ws is 16B-aligned
            p[r][1] = v.x; p[r][2] = v.y; p[r][3] = v.z; p[r][4] = v.w;
            p[r][0] = (ws > 0)      ? row[-1] : 0.f;
            p[r][5] = (ws + 4 < WW) ? row[4]  : 0.f;
        } else {
            #pragma unroll
            for (int j = 0; j < 6; ++j) p[r][j] = 0.f;
        }
    }

    const float inv9 = 1.0f / 9.0f;
    float mean[4] = {0.f, 0.f, 0.f, 0.f};
    #pragma unroll
    for (int k = 0; k < KK; ++k) {
        const int kh = k / 3, kw = k - kh * 3;
        #pragma unroll
        for (int j = 0; j < 4; ++j)
            mean[j] += p[kh][j + kw] * w9[k];
    }
    #pragma unroll
    for (int j = 0; j < 4; ++j) mean[j] *= inv9;

    float* onb = out + (size_t)b * (NN * CC * KK) * LL
                     + (size_t)((n * CC + c) * KK) * LL
                     + (size_t)(h * WW + ws);
    #pragma unroll
    for (int k = 0; k < KK; ++k) {
        const int kh = k / 3, kw = k - kh * 3;
        vf4 o;
        #pragma unroll
        for (int j = 0; j < 4; ++j) {
            const float v = p[kh][j + kw] * w9[k];
            const float d = v - mean[j];
            o[j] = d * d * sinv + bias;
        }
        // regular cached store: fillBufferAligned proves this path streams at 6.35 TB/s
        *(vf4*)(onb + (size_t)k * LL) = o;
    }
}

extern "C" void kernel_launch(void* const* d_in, const int* in_sizes, int n_in,
                              void* d_out, int out_size, void* d_ws, size_t ws_size,
                              hipStream_t stream) {
    const float* arr = (const float*)d_in[0];
    const float* Wt  = (const float*)d_in[1];
    const float* Bb  = (const float*)d_in[2];
    float* out = (float*)d_out;

    // threads total = B*N*C*H*(W/4) = 4*8*8*128*32 = 1,048,576 -> 4096 blocks
    const int threads = 256;
    const int blocks = BB * NN * CC * 16;  // 4096
    tvar_kernel<<<blocks, threads, 0, stream>>>(arr, Wt, Bb, out);
}